// Round 1
// baseline (346.887 us; speedup 1.0000x reference)
//
#include <hip/hip_runtime.h>

// out[row] = sum_{f=0..1023} x[row*1024+f]  *  sum_{k=0..9} coeffs[k]
// x: (16*4096) rows x 1024 fp32.  Memory-bound: 256 MiB read.
// One 64-lane wave per row; 4 float4 loads per lane (64*4*4 = 1024 elems).

#define F_DIM 1024
#define ROWS_PER_BLOCK 4  // 256 threads = 4 waves, one row each

__global__ __launch_bounds__(256) void spline_rowsum_kernel(
    const float* __restrict__ x,
    const float* __restrict__ coeffs,
    float* __restrict__ out,
    long long nrows) {
  const int wave = threadIdx.x >> 6;   // 0..3
  const int lane = threadIdx.x & 63;
  const long long row = (long long)blockIdx.x * ROWS_PER_BLOCK + wave;
  if (row >= nrows) return;

  const float4* __restrict__ xr =
      reinterpret_cast<const float4*>(x + row * (long long)F_DIM);

  float s = 0.0f;
#pragma unroll
  for (int j = 0; j < 4; ++j) {
    float4 v = xr[j * 64 + lane];   // lanes contiguous: coalesced 1 KiB/wave
    s += (v.x + v.y) + (v.z + v.w);
  }

  // wave-64 butterfly reduction
#pragma unroll
  for (int off = 32; off > 0; off >>= 1)
    s += __shfl_down(s, off, 64);

  if (lane == 0) {
    float cs = 0.0f;
#pragma unroll
    for (int k = 0; k < 10; ++k) cs += coeffs[k];  // tiny, L2-resident
    out[row] = s * cs;
  }
}

extern "C" void kernel_launch(void* const* d_in, const int* in_sizes, int n_in,
                              void* d_out, int out_size, void* d_ws, size_t ws_size,
                              hipStream_t stream) {
  const float* x      = (const float*)d_in[0];   // 16*4096*1024 fp32
  const float* coeffs = (const float*)d_in[1];   // 10 fp32
  float* out          = (float*)d_out;           // 65536 fp32

  const long long nrows = (long long)out_size;   // 16*4096 = 65536
  const int blocks = (int)((nrows + ROWS_PER_BLOCK - 1) / ROWS_PER_BLOCK);
  spline_rowsum_kernel<<<blocks, 256, 0, stream>>>(x, coeffs, out, nrows);
}

// Round 3
// 329.396 us; speedup vs baseline: 1.0531x; 1.0531x over previous
//
#include <hip/hip_runtime.h>

// out[row] = (sum_{f<1024} x[row,f]) * (sum coeffs), rows = 16*4096 = 65536.
// Pure streaming reduction: 256 MiB read, 256 KiB write -> HBM-bound,
// floor ~43 us at 6.3 TB/s achievable.
//
// Structure: 2048 blocks x 256 threads = 8192 waves (8 blocks/CU, full
// 32-wave occupancy). Each wave owns rows {w + i*8192}, processed 2 rows
// per loop iteration -> 8 independent float4 nontemporal loads in flight
// before the shuffle reduction (which is off the load critical path).

typedef float vf4 __attribute__((ext_vector_type(4)));  // clang vector: ok for nontemporal builtin

#define WAVES_PER_BLOCK 4
#define NUM_BLOCKS 2048

__global__ __launch_bounds__(256) void spline_rowsum_kernel(
    const float* __restrict__ x,
    const float* __restrict__ coeffs,
    float* __restrict__ out,
    int nrows) {
  const int lane = threadIdx.x & 63;
  const int w = blockIdx.x * WAVES_PER_BLOCK + (threadIdx.x >> 6);
  const int total_waves = NUM_BLOCKS * WAVES_PER_BLOCK;  // 8192

  float cs = 0.0f;
#pragma unroll
  for (int k = 0; k < 10; ++k) cs += coeffs[k];  // scalar, L2-resident

  int r = w;
  // main loop: 2 rows per iteration, 8 x 16B loads outstanding
  for (; r + total_waves < nrows; r += 2 * total_waves) {
    const vf4* xa = reinterpret_cast<const vf4*>(x + (long long)r * 1024) + lane;
    const vf4* xb = reinterpret_cast<const vf4*>(
                        x + (long long)(r + total_waves) * 1024) + lane;

    vf4 a0 = __builtin_nontemporal_load(xa + 0 * 64);
    vf4 a1 = __builtin_nontemporal_load(xa + 1 * 64);
    vf4 a2 = __builtin_nontemporal_load(xa + 2 * 64);
    vf4 a3 = __builtin_nontemporal_load(xa + 3 * 64);
    vf4 b0 = __builtin_nontemporal_load(xb + 0 * 64);
    vf4 b1 = __builtin_nontemporal_load(xb + 1 * 64);
    vf4 b2 = __builtin_nontemporal_load(xb + 2 * 64);
    vf4 b3 = __builtin_nontemporal_load(xb + 3 * 64);

    float sa = ((a0.x + a0.y) + (a0.z + a0.w)) + ((a1.x + a1.y) + (a1.z + a1.w))
             + ((a2.x + a2.y) + (a2.z + a2.w)) + ((a3.x + a3.y) + (a3.z + a3.w));
    float sb = ((b0.x + b0.y) + (b0.z + b0.w)) + ((b1.x + b1.y) + (b1.z + b1.w))
             + ((b2.x + b2.y) + (b2.z + b2.w)) + ((b3.x + b3.y) + (b3.z + b3.w));

#pragma unroll
    for (int off = 32; off > 0; off >>= 1) {
      sa += __shfl_down(sa, off, 64);
      sb += __shfl_down(sb, off, 64);
    }
    if (lane == 0) {
      out[r] = sa * cs;
      out[r + total_waves] = sb * cs;
    }
  }
  // tail: at most one row left for this wave
  if (r < nrows) {
    const vf4* xa = reinterpret_cast<const vf4*>(x + (long long)r * 1024) + lane;
    vf4 a0 = __builtin_nontemporal_load(xa + 0 * 64);
    vf4 a1 = __builtin_nontemporal_load(xa + 1 * 64);
    vf4 a2 = __builtin_nontemporal_load(xa + 2 * 64);
    vf4 a3 = __builtin_nontemporal_load(xa + 3 * 64);
    float sa = ((a0.x + a0.y) + (a0.z + a0.w)) + ((a1.x + a1.y) + (a1.z + a1.w))
             + ((a2.x + a2.y) + (a2.z + a2.w)) + ((a3.x + a3.y) + (a3.z + a3.w));
#pragma unroll
    for (int off = 32; off > 0; off >>= 1) sa += __shfl_down(sa, off, 64);
    if (lane == 0) out[r] = sa * cs;
  }
}

extern "C" void kernel_launch(void* const* d_in, const int* in_sizes, int n_in,
                              void* d_out, int out_size, void* d_ws, size_t ws_size,
                              hipStream_t stream) {
  const float* x      = (const float*)d_in[0];   // 16*4096*1024 fp32
  const float* coeffs = (const float*)d_in[1];   // 10 fp32
  float* out          = (float*)d_out;           // 65536 fp32

  spline_rowsum_kernel<<<NUM_BLOCKS, 256, 0, stream>>>(x, coeffs, out, out_size);
}